// Round 2
// baseline (2940.506 us; speedup 1.0000x reference)
//
#include <hip/hip_runtime.h>
#include <hip/hip_bf16.h>
#include <cstdint>
#include <cstddef>

namespace {

constexpr int kB = 128;
constexpr int kS = 512;
constexpr int kM = kB * kS;   // 65536 rows

__device__ __forceinline__ float sig_(float x) { return 1.f / (1.f + __expf(-x)); }
__device__ __forceinline__ float tanh_(float x) {
  float e = __expf(2.f * x);
  return 1.f - 2.f / (e + 1.f);
}

__device__ __forceinline__ float xg_ld(const float* p, size_t i) { return p[i]; }
__device__ __forceinline__ float xg_ld(const __hip_bfloat16* p, size_t i) { return __bfloat162float(p[i]); }
__device__ __forceinline__ void xg_st(float* p, size_t i, float v) { p[i] = v; }
__device__ __forceinline__ void xg_st(__hip_bfloat16* p, size_t i, float v) { p[i] = __float2bfloat16(v); }

// ---------------------------------------------------------------------------
// K1: per-tap char projection table: tbl[(tap*97+ch)*64+f] = sum_c emb[ch][c]*W_k[f][c][dk]
// taps 0..2 -> k3 (dk 0..2), 3..7 -> k5, 8..14 -> k7
// ---------------------------------------------------------------------------
__global__ void k_table(const float* __restrict__ emb,
                        const float* __restrict__ cw3,
                        const float* __restrict__ cw5,
                        const float* __restrict__ cw7,
                        float* __restrict__ tbl) {
  int e = blockIdx.x;           // 0..15*97-1
  int tap = e / 97, ch = e % 97;
  int f = threadIdx.x;          // 0..63
  const float* w; int kk, dk;
  if (tap < 3)      { w = cw3; kk = 3; dk = tap; }
  else if (tap < 8) { w = cw5; kk = 5; dk = tap - 3; }
  else              { w = cw7; kk = 7; dk = tap - 8; }
  const float* er = emb + ch * 128;
  float s = 0.f;
  for (int c = 0; c < 128; ++c) s = fmaf(er[c], w[(f * 128 + c) * kk + dk], s);
  tbl[(size_t)e * 64 + f] = s;
}

// ---------------------------------------------------------------------------
// K2: conv via table gathers + bias + relu.  out (B*S, 192)
// block: 192 threads (wave0->k3 filters 0..63, wave1->k5, wave2->k7), 64 positions
// ---------------------------------------------------------------------------
__global__ void k_conv(const int* __restrict__ x, const float* __restrict__ tbl,
                       const float* __restrict__ cb3, const float* __restrict__ cb5,
                       const float* __restrict__ cb7, float* __restrict__ outA) {
  __shared__ int chs[70];
  int b = blockIdx.x >> 3;
  int s0 = (blockIdx.x & 7) << 6;
  int tid = threadIdx.x;
  if (tid < 70) {
    int g = s0 - 3 + tid;
    chs[tid] = (g >= 0 && g < kS) ? x[b * kS + g] : 0;   // char 0 => zero row (emb[0]=0)
  }
  __syncthreads();
  int wv = tid >> 6;            // which conv
  int f = tid & 63;
  int ntap, tap0, half; const float* cb;
  if (wv == 0)      { ntap = 3; tap0 = 0; half = 1; cb = cb3; }
  else if (wv == 1) { ntap = 5; tap0 = 3; half = 2; cb = cb5; }
  else              { ntap = 7; tap0 = 8; half = 3; cb = cb7; }
  float bias = cb[f];
  for (int p = 0; p < 64; ++p) {
    float acc = bias;
    for (int dk = 0; dk < ntap; ++dk) {
      int c = chs[p + 3 - half + dk];
      acc += tbl[(size_t)((tap0 + dk) * 97 + c) * 64 + f];
    }
    outA[(size_t)(b * kS + s0 + p) * 192 + wv * 64 + f] = fmaxf(acc, 0.f);
  }
}

// ---------------------------------------------------------------------------
// K3: highway, fused dual GEMM.  B[row,j] = t*relu(a)+(1-t)*A[row,j]
// tiles 64M x 64N, K=192, 256 threads, thread = 4x4 micro-tile x 2 accumulators
// ---------------------------------------------------------------------------
__global__ __launch_bounds__(256) void k_highway(
    const float* __restrict__ A,
    const float* __restrict__ Wa, const float* __restrict__ Ba,
    const float* __restrict__ Wg, const float* __restrict__ Bg,
    float* __restrict__ outB) {
  __shared__ float Als[16][68];
  __shared__ float Was[16][68];
  __shared__ float Wgs[16][68];
  int tid = threadIdx.x;
  int tm = tid & 15, tn = tid >> 4;
  int m0 = blockIdx.x * 64, n0 = blockIdx.y * 64;
  int lm = tid >> 2, lk = (tid & 3) * 4;
  float aa[4][4] = {}, ag[4][4] = {};
  for (int kc = 0; kc < 192; kc += 16) {
    __syncthreads();
    float4 a4 = *(const float4*)(A  + (size_t)(m0 + lm) * 192 + kc + lk);
    float4 w4 = *(const float4*)(Wa + (size_t)(n0 + lm) * 192 + kc + lk);
    float4 g4 = *(const float4*)(Wg + (size_t)(n0 + lm) * 192 + kc + lk);
    Als[lk + 0][lm] = a4.x; Als[lk + 1][lm] = a4.y; Als[lk + 2][lm] = a4.z; Als[lk + 3][lm] = a4.w;
    Was[lk + 0][lm] = w4.x; Was[lk + 1][lm] = w4.y; Was[lk + 2][lm] = w4.z; Was[lk + 3][lm] = w4.w;
    Wgs[lk + 0][lm] = g4.x; Wgs[lk + 1][lm] = g4.y; Wgs[lk + 2][lm] = g4.z; Wgs[lk + 3][lm] = g4.w;
    __syncthreads();
#pragma unroll
    for (int kk = 0; kk < 16; ++kk) {
      float4 av = *(const float4*)&Als[kk][tm * 4];
      float4 wv = *(const float4*)&Was[kk][tn * 4];
      float4 gv = *(const float4*)&Wgs[kk][tn * 4];
      float ar[4] = {av.x, av.y, av.z, av.w};
      float wr[4] = {wv.x, wv.y, wv.z, wv.w};
      float gr[4] = {gv.x, gv.y, gv.z, gv.w};
#pragma unroll
      for (int r = 0; r < 4; ++r)
#pragma unroll
        for (int c2 = 0; c2 < 4; ++c2) {
          aa[r][c2] = fmaf(ar[r], wr[c2], aa[r][c2]);
          ag[r][c2] = fmaf(ar[r], gr[c2], ag[r][c2]);
        }
    }
  }
#pragma unroll
  for (int r = 0; r < 4; ++r) {
    int row = m0 + tm * 4 + r;
    const float* Arow = A + (size_t)row * 192;
#pragma unroll
    for (int c2 = 0; c2 < 4; ++c2) {
      int col = n0 + tn * 4 + c2;
      float av = aa[r][c2] + Ba[col];
      float gv = ag[r][c2] + Bg[col];
      float tt = sig_(gv);
      outB[(size_t)row * 192 + col] = tt * fmaxf(av, 0.f) + (1.f - tt) * Arow[col];
    }
  }
}

// ---------------------------------------------------------------------------
// K4: LSTM input projection GEMM. xg[row, j] = A[row,:]@W[j,:] + bias[j]
// N may be 1024 (fwd cols 0..511, bwd 512..1023) or 512 (single direction)
// ---------------------------------------------------------------------------
template <typename XGT>
__global__ __launch_bounds__(256) void k_proj(
    const float* __restrict__ A, int K,
    const float* __restrict__ Wf, const float* __restrict__ bf,
    const float* __restrict__ Wb, const float* __restrict__ bb,
    XGT* __restrict__ xg, int Ntot) {
  __shared__ float Als[16][68];
  __shared__ float Wls[16][68];
  int tid = threadIdx.x;
  int tm = tid & 15, tn = tid >> 4;
  int m0 = blockIdx.x * 64, n0 = blockIdx.y * 64;
  const float* W = Wf; const float* bias = bf; int nb = n0;
  if (n0 >= 512) { W = Wb; bias = bb; nb = n0 - 512; }
  int lm = tid >> 2, lk = (tid & 3) * 4;
  float acc[4][4] = {};
  for (int kc = 0; kc < K; kc += 16) {
    __syncthreads();
    float4 a4 = *(const float4*)(A + (size_t)(m0 + lm) * K + kc + lk);
    float4 w4 = *(const float4*)(W + (size_t)(nb + lm) * K + kc + lk);
    Als[lk + 0][lm] = a4.x; Als[lk + 1][lm] = a4.y; Als[lk + 2][lm] = a4.z; Als[lk + 3][lm] = a4.w;
    Wls[lk + 0][lm] = w4.x; Wls[lk + 1][lm] = w4.y; Wls[lk + 2][lm] = w4.z; Wls[lk + 3][lm] = w4.w;
    __syncthreads();
#pragma unroll
    for (int kk = 0; kk < 16; ++kk) {
      float4 av = *(const float4*)&Als[kk][tm * 4];
      float4 wv = *(const float4*)&Wls[kk][tn * 4];
      float ar[4] = {av.x, av.y, av.z, av.w};
      float wr[4] = {wv.x, wv.y, wv.z, wv.w};
#pragma unroll
      for (int r = 0; r < 4; ++r)
#pragma unroll
        for (int c2 = 0; c2 < 4; ++c2)
          acc[r][c2] = fmaf(ar[r], wr[c2], acc[r][c2]);
    }
  }
#pragma unroll
  for (int r = 0; r < 4; ++r) {
    int row = m0 + tm * 4 + r;
#pragma unroll
    for (int c2 = 0; c2 < 4; ++c2) {
      int col = n0 + tn * 4 + c2;
      xg_st(xg, (size_t)row * Ntot + col, acc[r][c2] + bias[nb - n0 + col]);
    }
  }
}

// ---------------------------------------------------------------------------
// K5: LSTM recurrence. One block (1024 thr) per (sequence, direction).
// whh rows in registers (thread: rows jj & jj+256, K-quarter q), h broadcast via LDS,
// xg prefetched one step ahead. out[(b*S+t)*256 + dir*128 + u]
// ---------------------------------------------------------------------------
template <typename XGT>
__global__ __launch_bounds__(1024, 4) void k_rec(
    const XGT* __restrict__ xg, int xg_stride, int dual,
    const float* __restrict__ whhF, const float* __restrict__ whhB,
    float* __restrict__ out, int dir_base) {
  int nb = blockIdx.x;
  int seq = nb & (kB - 1);
  int dir = dir_base + (nb >> 7);
  const float* __restrict__ whh = dir ? whhB : whhF;
  const int col0 = dual ? dir * 512 : 0;
  const bool rev = (dir == 1);
  int tid = threadIdx.x;
  int q = tid >> 8;        // K quarter (wave-uniform)
  int jj = tid & 255;      // outputs jj and jj+256

  float w0[32], w1[32];
  {
    const float4* p0 = reinterpret_cast<const float4*>(whh + jj * 128 + q * 32);
    const float4* p1 = reinterpret_cast<const float4*>(whh + (jj + 256) * 128 + q * 32);
#pragma unroll
    for (int v = 0; v < 8; ++v) {
      float4 t0 = p0[v]; w0[4 * v] = t0.x; w0[4 * v + 1] = t0.y; w0[4 * v + 2] = t0.z; w0[4 * v + 3] = t0.w;
      float4 t1 = p1[v]; w1[4 * v] = t1.x; w1[4 * v + 1] = t1.y; w1[4 * v + 2] = t1.z; w1[4 * v + 3] = t1.w;
    }
  }
  __shared__ float hbuf[128];
  __shared__ float xbuf[512];
  __shared__ float zp[512 * 5];   // [j][q], pad 5 to spread banks
  if (tid < 128) hbuf[tid] = 0.f;
  float c = 0.f;

  auto base_of = [&](int step) -> size_t {
    int tt = rev ? (kS - 1 - step) : step;
    return (size_t)(seq * kS + tt) * xg_stride + col0;
  };
  float xv = 0.f;
  if (tid < 512) xv = xg_ld(xg, base_of(0) + tid);
  __syncthreads();

  for (int t = 0; t < kS; ++t) {
    int tt = rev ? (kS - 1 - t) : t;
    float p0 = 0.f, p1 = 0.f;
    const float4* hb = reinterpret_cast<const float4*>(hbuf + q * 32);
#pragma unroll
    for (int v = 0; v < 8; ++v) {
      float4 h4 = hb[v];
      p0 = fmaf(w0[4 * v + 0], h4.x, p0);
      p0 = fmaf(w0[4 * v + 1], h4.y, p0);
      p0 = fmaf(w0[4 * v + 2], h4.z, p0);
      p0 = fmaf(w0[4 * v + 3], h4.w, p0);
      p1 = fmaf(w1[4 * v + 0], h4.x, p1);
      p1 = fmaf(w1[4 * v + 1], h4.y, p1);
      p1 = fmaf(w1[4 * v + 2], h4.z, p1);
      p1 = fmaf(w1[4 * v + 3], h4.w, p1);
    }
    zp[jj * 5 + q] = p0;
    zp[(jj + 256) * 5 + q] = p1;
    if (tid < 512) xbuf[tid] = xv;
    // prefetch next step's xg (hidden behind barrier + gate phase + next partials)
    int tnx = (t + 1 < kS) ? (t + 1) : (kS - 1);
    if (tid < 512) xv = xg_ld(xg, base_of(tnx) + tid);
    __syncthreads();
    if (tid < 128) {
      int u = tid;
      float zi = xbuf[u]       + zp[u * 5 + 0] + zp[u * 5 + 1] + zp[u * 5 + 2] + zp[u * 5 + 3];
      float zf = xbuf[u + 128] + zp[(u + 128) * 5 + 0] + zp[(u + 128) * 5 + 1] + zp[(u + 128) * 5 + 2] + zp[(u + 128) * 5 + 3];
      float zg = xbuf[u + 256] + zp[(u + 256) * 5 + 0] + zp[(u + 256) * 5 + 1] + zp[(u + 256) * 5 + 2] + zp[(u + 256) * 5 + 3];
      float zo = xbuf[u + 384] + zp[(u + 384) * 5 + 0] + zp[(u + 384) * 5 + 1] + zp[(u + 384) * 5 + 2] + zp[(u + 384) * 5 + 3];
      float ig = sig_(zi), fg = sig_(zf), gv = tanh_(zg), og = sig_(zo);
      c = fg * c + ig * gv;
      float h = og * tanh_(c);
      hbuf[u] = h;
      out[(size_t)(seq * kS + tt) * 256 + dir * 128 + u] = h;
    }
    __syncthreads();
  }
}

// ---------------------------------------------------------------------------
// K6: classifier + char mask. em[row, j] = out1[row,:]@cls_w[j,:] + cls_b[j]  (or NEG)
// block: 256 thr = 64 rows x 4 K-quarters
// ---------------------------------------------------------------------------
__global__ __launch_bounds__(256) void k_cls(
    const float* __restrict__ out1, const float* __restrict__ cls_w,
    const float* __restrict__ cls_b, const int* __restrict__ x,
    float* __restrict__ em) {
  __shared__ float W[17 * 256];
  __shared__ float part[64 * 4 * 17];
  int tid = threadIdx.x;
  for (int i = tid; i < 17 * 256; i += 256) W[i] = cls_w[i];
  __syncthreads();
  int r = tid >> 2, q = tid & 3;
  size_t row = (size_t)blockIdx.x * 64 + r;
  float acc[17];
#pragma unroll
  for (int j = 0; j < 17; ++j) acc[j] = 0.f;
  const float4* a4p = (const float4*)(out1 + row * 256 + q * 64);
  for (int i = 0; i < 16; ++i) {
    float4 a4 = a4p[i];
#pragma unroll
    for (int j = 0; j < 17; ++j) {
      float4 w4 = *(const float4*)&W[j * 256 + q * 64 + i * 4];
      acc[j] += a4.x * w4.x + a4.y * w4.y + a4.z * w4.z + a4.w * w4.w;
    }
  }
#pragma unroll
  for (int j = 0; j < 17; ++j) part[(r * 4 + q) * 17 + j] = acc[j];
  __syncthreads();
  for (int idx = tid; idx < 64 * 17; idx += 256) {
    int rr = idx / 17, j = idx % 17;
    size_t row2 = (size_t)blockIdx.x * 64 + rr;
    float v = part[(rr * 4 + 0) * 17 + j] + part[(rr * 4 + 1) * 17 + j] +
              part[(rr * 4 + 2) * 17 + j] + part[(rr * 4 + 3) * 17 + j] + cls_b[j];
    em[row2 * 17 + j] = (x[row2] != 0) ? v : -1e9f;
  }
}

// ---------------------------------------------------------------------------
// K7: CRF loss per sequence (1 wave / block). res[b] = logZ - score
// ---------------------------------------------------------------------------
__global__ __launch_bounds__(64) void k_crf(
    const float* __restrict__ em, const int* __restrict__ tags,
    const float* __restrict__ mask, const float* __restrict__ trans,
    const float* __restrict__ start_t, const float* __restrict__ end_t,
    float* __restrict__ res) {
  int b = blockIdx.x;
  int lane = threadIdx.x;
  const float* emB = em + (size_t)b * kS * 17;
  const int* tg = tags + b * kS;
  const float* mk = mask + b * kS;

  float tcol[17];
  if (lane < 17) {
#pragma unroll
    for (int i = 0; i < 17; ++i) tcol[i] = trans[i * 17 + lane];
  }
  float sc = 0.f, msum = 0.f;
  for (int t = lane; t < kS; t += 64) msum += mk[t];
  for (int t = 1 + lane; t < kS; t += 64)
    sc += (trans[tg[t - 1] * 17 + tg[t]] + emB[(size_t)t * 17 + tg[t]]) * mk[t];
#pragma unroll
  for (int o = 32; o; o >>= 1) { sc += __shfl_xor(sc, o); msum += __shfl_xor(msum, o); }

  __shared__ float al[17];
  if (lane < 17) al[lane] = start_t[lane] + emB[lane];
  __syncthreads();
  for (int t = 1; t < kS; ++t) {
    float nxt = 0.f;
    if (lane < 17) {
      float v[17]; float mx = -3.4e38f;
#pragma unroll
      for (int i = 0; i < 17; ++i) { v[i] = al[i] + tcol[i]; mx = fmaxf(mx, v[i]); }
      float s = 0.f;
#pragma unroll
      for (int i = 0; i < 17; ++i) s += __expf(v[i] - mx);
      float m = mk[t];
      nxt = (mx + __logf(s) + emB[(size_t)t * 17 + lane]) * m + al[lane] * (1.f - m);
    }
    __syncthreads();
    if (lane < 17) al[lane] = nxt;
    __syncthreads();
  }
  float val = (lane < 17) ? al[lane] + end_t[lane] : -3.4e38f;
  float mx = val;
#pragma unroll
  for (int o = 32; o; o >>= 1) mx = fmaxf(mx, __shfl_xor(mx, o));
  float s = (lane < 17) ? __expf(val - mx) : 0.f;
#pragma unroll
  for (int o = 32; o; o >>= 1) s += __shfl_xor(s, o);
  float logZ = mx + __logf(s);
  if (lane == 0) {
    float score = sc + start_t[tg[0]] + emB[tg[0]];
    int last_real = (int)(msum + 0.5f) - 1;
    if (last_real >= 0) score += end_t[tg[last_real]];
    res[b] = logZ - score;
  }
}

// K8: deterministic mean over 128 sequences -> d_out[0]
__global__ void k_loss(const float* __restrict__ res, float* __restrict__ out) {
  __shared__ float s[128];
  int tid = threadIdx.x;
  s[tid] = res[tid];
  __syncthreads();
  for (int off = 64; off; off >>= 1) {
    if (tid < off) s[tid] += s[tid + off];
    __syncthreads();
  }
  if (tid == 0) out[0] = s[0] / 128.f;
}

}  // namespace

extern "C" void kernel_launch(void* const* d_in, const int* in_sizes, int n_in,
                              void* d_out, int out_size, void* d_ws, size_t ws_size,
                              hipStream_t stream) {
  (void)in_sizes; (void)n_in; (void)out_size;
  const int*   x       = (const int*)  d_in[0];
  const int*   tags    = (const int*)  d_in[1];
  const float* mask    = (const float*)d_in[2];
  const float* emb     = (const float*)d_in[3];
  const float* cw3     = (const float*)d_in[4];
  const float* cb3     = (const float*)d_in[5];
  const float* cw5     = (const float*)d_in[6];
  const float* cb5     = (const float*)d_in[7];
  const float* cw7     = (const float*)d_in[8];
  const float* cb7     = (const float*)d_in[9];
  const float* hw_w    = (const float*)d_in[10];
  const float* hw_b    = (const float*)d_in[11];
  const float* hwg_w   = (const float*)d_in[12];
  const float* hwg_b   = (const float*)d_in[13];
  const float* wih0f   = (const float*)d_in[14];
  const float* whh0f   = (const float*)d_in[15];
  const float* b0f     = (const float*)d_in[16];
  const float* wih0b   = (const float*)d_in[17];
  const float* whh0b   = (const float*)d_in[18];
  const float* b0b     = (const float*)d_in[19];
  const float* wih1f   = (const float*)d_in[20];
  const float* whh1f   = (const float*)d_in[21];
  const float* b1f     = (const float*)d_in[22];
  const float* wih1b   = (const float*)d_in[23];
  const float* whh1b   = (const float*)d_in[24];
  const float* b1b     = (const float*)d_in[25];
  const float* cls_w   = (const float*)d_in[26];
  const float* cls_b   = (const float*)d_in[27];
  const float* trans   = (const float*)d_in[28];
  const float* start_t = (const float*)d_in[29];
  const float* end_t   = (const float*)d_in[30];

  char* ws = (char*)d_ws;
  const size_t OFF_A = 393216;                          // conv h (later out1 alias)
  const size_t OFF_B = OFF_A + (size_t)kM * 192 * 4;    // hw
  const size_t OFF_D = OFF_B + (size_t)kM * 192 * 4;    // out0 (later em alias)
  const size_t OFF_C = OFF_D + (size_t)kM * 256 * 4;    // xg
  float* tbl  = (float*)ws;
  float* bufA = (float*)(ws + OFF_A);
  float* bufB = (float*)(ws + OFF_B);
  float* out0 = (float*)(ws + OFF_D);
  float* out1 = bufA;                                   // conv h & hw dead by then
  float* em   = (float*)(ws + OFF_D);                   // out0 dead by then
  float* resv = (float*)(ws + OFF_D + (size_t)kM * 17 * 4);

  k_table<<<15 * 97, 64, 0, stream>>>(emb, cw3, cw5, cw7, tbl);
  k_conv<<<kB * (kS / 64), 192, 0, stream>>>(x, tbl, cb3, cb5, cb7, bufA);
  k_highway<<<dim3(kM / 64, 3), 256, 0, stream>>>(bufA, hw_w, hw_b, hwg_w, hwg_b, bufB);

  const size_t needF32Dual  = OFF_C + (size_t)kM * 1024 * 4;  // ~437 MB
  const size_t needF32Split = OFF_C + (size_t)kM * 512 * 4;   // ~302 MB

  if (ws_size >= needF32Dual) {
    float* xg = (float*)(ws + OFF_C);
    k_proj<float><<<dim3(kM / 64, 16), 256, 0, stream>>>(bufB, 192, wih0f, b0f, wih0b, b0b, xg, 1024);
    k_rec<float><<<256, 1024, 0, stream>>>(xg, 1024, 1, whh0f, whh0b, out0, 0);
    k_proj<float><<<dim3(kM / 64, 16), 256, 0, stream>>>(out0, 256, wih1f, b1f, wih1b, b1b, xg, 1024);
    k_rec<float><<<256, 1024, 0, stream>>>(xg, 1024, 1, whh1f, whh1b, out1, 0);
  } else if (ws_size >= needF32Split) {
    float* xg = (float*)(ws + OFF_C);
    k_proj<float><<<dim3(kM / 64, 8), 256, 0, stream>>>(bufB, 192, wih0f, b0f, nullptr, nullptr, xg, 512);
    k_rec<float><<<128, 1024, 0, stream>>>(xg, 512, 0, whh0f, whh0b, out0, 0);
    k_proj<float><<<dim3(kM / 64, 8), 256, 0, stream>>>(bufB, 192, wih0b, b0b, nullptr, nullptr, xg, 512);
    k_rec<float><<<128, 1024, 0, stream>>>(xg, 512, 0, whh0f, whh0b, out0, 1);
    k_proj<float><<<dim3(kM / 64, 8), 256, 0, stream>>>(out0, 256, wih1f, b1f, nullptr, nullptr, xg, 512);
    k_rec<float><<<128, 1024, 0, stream>>>(xg, 512, 0, whh1f, whh1b, out1, 0);
    k_proj<float><<<dim3(kM / 64, 8), 256, 0, stream>>>(out0, 256, wih1b, b1b, nullptr, nullptr, xg, 512);
    k_rec<float><<<128, 1024, 0, stream>>>(xg, 512, 0, whh1f, whh1b, out1, 1);
  } else {
    __hip_bfloat16* xg = (__hip_bfloat16*)(ws + OFF_C);
    k_proj<__hip_bfloat16><<<dim3(kM / 64, 8), 256, 0, stream>>>(bufB, 192, wih0f, b0f, nullptr, nullptr, xg, 512);
    k_rec<__hip_bfloat16><<<128, 1024, 0, stream>>>(xg, 512, 0, whh0f, whh0b, out0, 0);
    k_proj<__hip_bfloat16><<<dim3(kM / 64, 8), 256, 0, stream>>>(bufB, 192, wih0b, b0b, nullptr, nullptr, xg, 512);
    k_rec<__hip_bfloat16><<<128, 1024, 0, stream>>>(xg, 512, 0, whh0f, whh0b, out0, 1);
    k_proj<__hip_bfloat16><<<dim3(kM / 64, 8), 256, 0, stream>>>(out0, 256, wih1f, b1f, nullptr, nullptr, xg, 512);
    k_rec<__hip_bfloat16><<<128, 1024, 0, stream>>>(xg, 512, 0, whh1f, whh1b, out1, 0);
    k_proj<__hip_bfloat16><<<dim3(kM / 64, 8), 256, 0, stream>>>(out0, 256, wih1b, b1b, nullptr, nullptr, xg, 512);
    k_rec<__hip_bfloat16><<<128, 1024, 0, stream>>>(xg, 512, 0, whh1f, whh1b, out1, 1);
  }

  k_cls<<<kM / 64, 256, 0, stream>>>(out1, cls_w, cls_b, x, em);
  k_crf<<<kB, 64, 0, stream>>>(em, tags, mask, trans, start_t, end_t, resv);
  k_loss<<<1, 128, 0, stream>>>(resv, (float*)d_out);
}

// Round 3
// 2275.199 us; speedup vs baseline: 1.2924x; 1.2924x over previous
//
#include <hip/hip_runtime.h>
#include <hip/hip_bf16.h>
#include <cstdint>
#include <cstddef>

namespace {

constexpr int kB = 128;
constexpr int kS = 512;
constexpr int kM = kB * kS;   // 65536 rows

typedef __hip_bfloat16 bf16;

__device__ __forceinline__ float sig_(float x) { return 1.f / (1.f + __expf(-x)); }
__device__ __forceinline__ float tanh_(float x) {
  float e = __expf(2.f * x);
  return 1.f - 2.f / (e + 1.f);
}
__device__ __forceinline__ float b2f(bf16 h) { return __bfloat162float(h); }
__device__ __forceinline__ bf16 f2b(float f) { return __float2bfloat16(f); }

// unpack 8 bf16 (one uint4) -> 8 floats
__device__ __forceinline__ void unpack8(uint4 v, float* o) {
  o[0] = __uint_as_float(v.x << 16); o[1] = __uint_as_float(v.x & 0xffff0000u);
  o[2] = __uint_as_float(v.y << 16); o[3] = __uint_as_float(v.y & 0xffff0000u);
  o[4] = __uint_as_float(v.z << 16); o[5] = __uint_as_float(v.z & 0xffff0000u);
  o[6] = __uint_as_float(v.w << 16); o[7] = __uint_as_float(v.w & 0xffff0000u);
}

// ---------------------------------------------------------------------------
// K1: per-tap char projection table (fp32, 372KB)
// ---------------------------------------------------------------------------
__global__ void k_table(const float* __restrict__ emb,
                        const float* __restrict__ cw3,
                        const float* __restrict__ cw5,
                        const float* __restrict__ cw7,
                        float* __restrict__ tbl) {
  int e = blockIdx.x;           // 0..15*97-1
  int tap = e / 97, ch = e % 97;
  int f = threadIdx.x;          // 0..63
  const float* w; int kk, dk;
  if (tap < 3)      { w = cw3; kk = 3; dk = tap; }
  else if (tap < 8) { w = cw5; kk = 5; dk = tap - 3; }
  else              { w = cw7; kk = 7; dk = tap - 8; }
  const float* er = emb + ch * 128;
  float s = 0.f;
  for (int c = 0; c < 128; ++c) s = fmaf(er[c], w[(f * 128 + c) * kk + dk], s);
  tbl[(size_t)e * 64 + f] = s;
}

// ---------------------------------------------------------------------------
// K2: conv via table gathers + bias + relu -> bf16 (B*S, 192)
// ---------------------------------------------------------------------------
__global__ void k_conv(const int* __restrict__ x, const float* __restrict__ tbl,
                       const float* __restrict__ cb3, const float* __restrict__ cb5,
                       const float* __restrict__ cb7, bf16* __restrict__ outA) {
  __shared__ int chs[70];
  int b = blockIdx.x >> 3;
  int s0 = (blockIdx.x & 7) << 6;
  int tid = threadIdx.x;
  if (tid < 70) {
    int g = s0 - 3 + tid;
    chs[tid] = (g >= 0 && g < kS) ? x[b * kS + g] : 0;   // char 0 => zero row
  }
  __syncthreads();
  int wv = tid >> 6;
  int f = tid & 63;
  int ntap, tap0, half; const float* cb;
  if (wv == 0)      { ntap = 3; tap0 = 0; half = 1; cb = cb3; }
  else if (wv == 1) { ntap = 5; tap0 = 3; half = 2; cb = cb5; }
  else              { ntap = 7; tap0 = 8; half = 3; cb = cb7; }
  float bias = cb[f];
  for (int p = 0; p < 64; ++p) {
    float acc = bias;
    for (int dk = 0; dk < ntap; ++dk) {
      int c = chs[p + 3 - half + dk];
      acc += tbl[(size_t)((tap0 + dk) * 97 + c) * 64 + f];
    }
    outA[(size_t)(b * kS + s0 + p) * 192 + wv * 64 + f] = f2b(fmaxf(acc, 0.f));
  }
}

// ---------------------------------------------------------------------------
// K3: highway, fused dual GEMM. A bf16, weights fp32, out bf16.
// ---------------------------------------------------------------------------
__global__ __launch_bounds__(256) void k_highway(
    const bf16* __restrict__ A,
    const float* __restrict__ Wa, const float* __restrict__ Ba,
    const float* __restrict__ Wg, const float* __restrict__ Bg,
    bf16* __restrict__ outB) {
  __shared__ float Als[16][68];
  __shared__ float Was[16][68];
  __shared__ float Wgs[16][68];
  int tid = threadIdx.x;
  int tm = tid & 15, tn = tid >> 4;
  int m0 = blockIdx.x * 64, n0 = blockIdx.y * 64;
  int lm = tid >> 2, lk = (tid & 3) * 4;
  float aa[4][4] = {}, ag[4][4] = {};
  for (int kc = 0; kc < 192; kc += 16) {
    __syncthreads();
    if (tid < 128) {
      int row = tid & 63, koff = (tid >> 6) * 8;
      uint4 v = *(const uint4*)(A + (size_t)(m0 + row) * 192 + kc + koff);
      float f8[8]; unpack8(v, f8);
#pragma unroll
      for (int i = 0; i < 8; ++i) Als[koff + i][row] = f8[i];
    }
    float4 w4 = *(const float4*)(Wa + (size_t)(n0 + lm) * 192 + kc + lk);
    float4 g4 = *(const float4*)(Wg + (size_t)(n0 + lm) * 192 + kc + lk);
    Was[lk + 0][lm] = w4.x; Was[lk + 1][lm] = w4.y; Was[lk + 2][lm] = w4.z; Was[lk + 3][lm] = w4.w;
    Wgs[lk + 0][lm] = g4.x; Wgs[lk + 1][lm] = g4.y; Wgs[lk + 2][lm] = g4.z; Wgs[lk + 3][lm] = g4.w;
    __syncthreads();
#pragma unroll
    for (int kk = 0; kk < 16; ++kk) {
      float4 av = *(const float4*)&Als[kk][tm * 4];
      float4 wv = *(const float4*)&Was[kk][tn * 4];
      float4 gv = *(const float4*)&Wgs[kk][tn * 4];
      float ar[4] = {av.x, av.y, av.z, av.w};
      float wr[4] = {wv.x, wv.y, wv.z, wv.w};
      float gr[4] = {gv.x, gv.y, gv.z, gv.w};
#pragma unroll
      for (int r = 0; r < 4; ++r)
#pragma unroll
        for (int c2 = 0; c2 < 4; ++c2) {
          aa[r][c2] = fmaf(ar[r], wr[c2], aa[r][c2]);
          ag[r][c2] = fmaf(ar[r], gr[c2], ag[r][c2]);
        }
    }
  }
#pragma unroll
  for (int r = 0; r < 4; ++r) {
    int row = m0 + tm * 4 + r;
    const bf16* Arow = A + (size_t)row * 192;
#pragma unroll
    for (int c2 = 0; c2 < 4; ++c2) {
      int col = n0 + tn * 4 + c2;
      float av = aa[r][c2] + Ba[col];
      float gv = ag[r][c2] + Bg[col];
      float tt = sig_(gv);
      outB[(size_t)row * 192 + col] = f2b(tt * fmaxf(av, 0.f) + (1.f - tt) * b2f(Arow[col]));
    }
  }
}

// ---------------------------------------------------------------------------
// K4: LSTM input projection GEMM. A bf16 (stride K), W fp32, xg bf16 (stride 1024).
// Cols 0..511 = fwd (Wf,bf), 512..1023 = bwd (Wb,bb).
// ---------------------------------------------------------------------------
__global__ __launch_bounds__(256) void k_proj(
    const bf16* __restrict__ A, int K,
    const float* __restrict__ Wf, const float* __restrict__ bf,
    const float* __restrict__ Wb, const float* __restrict__ bb,
    bf16* __restrict__ xg) {
  __shared__ float Als[16][68];
  __shared__ float Wls[16][68];
  int tid = threadIdx.x;
  int tm = tid & 15, tn = tid >> 4;
  int m0 = blockIdx.x * 64, n0 = blockIdx.y * 64;
  const float* W = Wf; const float* bias = bf; int nb = n0;
  if (n0 >= 512) { W = Wb; bias = bb; nb = n0 - 512; }
  int lm = tid >> 2, lk = (tid & 3) * 4;
  float acc[4][4] = {};
  for (int kc = 0; kc < K; kc += 16) {
    __syncthreads();
    if (tid < 128) {
      int row = tid & 63, koff = (tid >> 6) * 8;
      uint4 v = *(const uint4*)(A + (size_t)(m0 + row) * K + kc + koff);
      float f8[8]; unpack8(v, f8);
#pragma unroll
      for (int i = 0; i < 8; ++i) Als[koff + i][row] = f8[i];
    }
    float4 w4 = *(const float4*)(W + (size_t)(nb + lm) * K + kc + lk);
    Wls[lk + 0][lm] = w4.x; Wls[lk + 1][lm] = w4.y; Wls[lk + 2][lm] = w4.z; Wls[lk + 3][lm] = w4.w;
    __syncthreads();
#pragma unroll
    for (int kk = 0; kk < 16; ++kk) {
      float4 av = *(const float4*)&Als[kk][tm * 4];
      float4 wv = *(const float4*)&Wls[kk][tn * 4];
      float ar[4] = {av.x, av.y, av.z, av.w};
      float wr[4] = {wv.x, wv.y, wv.z, wv.w};
#pragma unroll
      for (int r = 0; r < 4; ++r)
#pragma unroll
        for (int c2 = 0; c2 < 4; ++c2)
          acc[r][c2] = fmaf(ar[r], wr[c2], acc[r][c2]);
    }
  }
#pragma unroll
  for (int r = 0; r < 4; ++r) {
    int row = m0 + tm * 4 + r;
#pragma unroll
    for (int c2 = 0; c2 < 4; ++c2) {
      int col = n0 + tn * 4 + c2;
      xg[(size_t)row * 1024 + col] = f2b(acc[r][c2] + bias[nb - n0 + col]);
    }
  }
}

// ---------------------------------------------------------------------------
// K5: LSTM recurrence, dual-direction. Grid 256 = (seq 0..127) x (dir 0..1).
// 1024 threads: q = tid&3 (K-quarter, in-lane -> shfl reduce), jj = tid>>2.
// Thread computes partial dots for outputs jj and jj+256 over h[q*32..q*32+31].
// ---------------------------------------------------------------------------
__global__ __launch_bounds__(1024, 4) void k_rec(
    const bf16* __restrict__ xg,
    const float* __restrict__ whhF, const float* __restrict__ whhB,
    bf16* __restrict__ out) {
  int nb = blockIdx.x;
  int seq = nb & (kB - 1);
  int dir = nb >> 7;
  const float* __restrict__ whh = dir ? whhB : whhF;
  const int col0 = dir * 512;
  const bool rev = (dir == 1);
  int tid = threadIdx.x;
  int q = tid & 3;          // K quarter (in-lane)
  int jj = tid >> 2;        // outputs jj and jj+256

  float w0[32], w1[32];
  {
    const float4* p0 = reinterpret_cast<const float4*>(whh + jj * 128 + q * 32);
    const float4* p1 = reinterpret_cast<const float4*>(whh + (jj + 256) * 128 + q * 32);
#pragma unroll
    for (int v = 0; v < 8; ++v) {
      float4 t0 = p0[v]; w0[4 * v] = t0.x; w0[4 * v + 1] = t0.y; w0[4 * v + 2] = t0.z; w0[4 * v + 3] = t0.w;
      float4 t1 = p1[v]; w1[4 * v] = t1.x; w1[4 * v + 1] = t1.y; w1[4 * v + 2] = t1.z; w1[4 * v + 3] = t1.w;
    }
  }
  __shared__ float hbuf[128];
  __shared__ float xbuf[512];
  __shared__ float zs[512];
  if (tid < 128) hbuf[tid] = 0.f;
  float c = 0.f;

  auto base_of = [&](int step) -> size_t {
    int tt = rev ? (kS - 1 - step) : step;
    return (size_t)(seq * kS + tt) * 1024 + col0;
  };
  float xv = 0.f;
  if (tid < 512) xv = b2f(xg[base_of(0) + tid]);
  __syncthreads();

  for (int t = 0; t < kS; ++t) {
    int tt = rev ? (kS - 1 - t) : t;
    float p0 = 0.f, p1 = 0.f;
    const float4* hb = reinterpret_cast<const float4*>(hbuf + q * 32);
#pragma unroll
    for (int v = 0; v < 8; ++v) {
      float4 h4 = hb[v];
      p0 = fmaf(w0[4 * v + 0], h4.x, p0);
      p0 = fmaf(w0[4 * v + 1], h4.y, p0);
      p0 = fmaf(w0[4 * v + 2], h4.z, p0);
      p0 = fmaf(w0[4 * v + 3], h4.w, p0);
      p1 = fmaf(w1[4 * v + 0], h4.x, p1);
      p1 = fmaf(w1[4 * v + 1], h4.y, p1);
      p1 = fmaf(w1[4 * v + 2], h4.z, p1);
      p1 = fmaf(w1[4 * v + 3], h4.w, p1);
    }
    // quad-reduce over K quarters (lanes jj*4+q, q=0..3)
    p0 += __shfl_xor(p0, 1); p0 += __shfl_xor(p0, 2);
    p1 += __shfl_xor(p1, 1); p1 += __shfl_xor(p1, 2);
    if (q == 0) { zs[jj] = p0; zs[jj + 256] = p1; }
    if (tid < 512) xbuf[tid] = xv;
    int tnx = (t + 1 < kS) ? (t + 1) : (kS - 1);
    float xnew = 0.f;
    if (tid < 512) xnew = b2f(xg[base_of(tnx) + tid]);
    __syncthreads();
    if (tid < 128) {
      int u = tid;
      float zi = xbuf[u]       + zs[u];
      float zf = xbuf[u + 128] + zs[u + 128];
      float zg = xbuf[u + 256] + zs[u + 256];
      float zo = xbuf[u + 384] + zs[u + 384];
      float ig = sig_(zi), fg = sig_(zf), gv = tanh_(zg), og = sig_(zo);
      c = fg * c + ig * gv;
      float h = og * tanh_(c);
      hbuf[u] = h;
      out[(size_t)(seq * kS + tt) * 256 + dir * 128 + u] = f2b(h);
    }
    xv = xnew;
    __syncthreads();
  }
}

// ---------------------------------------------------------------------------
// K6: classifier + char mask. out1 bf16 -> em fp32 (or NEG)
// ---------------------------------------------------------------------------
__global__ __launch_bounds__(256) void k_cls(
    const bf16* __restrict__ out1, const float* __restrict__ cls_w,
    const float* __restrict__ cls_b, const int* __restrict__ x,
    float* __restrict__ em) {
  __shared__ float W[17 * 256];
  __shared__ float part[64 * 4 * 17];
  int tid = threadIdx.x;
  for (int i = tid; i < 17 * 256; i += 256) W[i] = cls_w[i];
  __syncthreads();
  int r = tid >> 2, q = tid & 3;
  size_t row = (size_t)blockIdx.x * 64 + r;
  float acc[17];
#pragma unroll
  for (int j = 0; j < 17; ++j) acc[j] = 0.f;
  const uint4* a4p = (const uint4*)(out1 + row * 256 + q * 64);
  for (int i = 0; i < 8; ++i) {
    float f8[8]; unpack8(a4p[i], f8);
#pragma unroll
    for (int j = 0; j < 17; ++j) {
      const float* wr = &W[j * 256 + q * 64 + i * 8];
#pragma unroll
      for (int e = 0; e < 8; ++e) acc[j] = fmaf(f8[e], wr[e], acc[j]);
    }
  }
#pragma unroll
  for (int j = 0; j < 17; ++j) part[(r * 4 + q) * 17 + j] = acc[j];
  __syncthreads();
  for (int idx = tid; idx < 64 * 17; idx += 256) {
    int rr = idx / 17, j = idx % 17;
    size_t row2 = (size_t)blockIdx.x * 64 + rr;
    float v = part[(rr * 4 + 0) * 17 + j] + part[(rr * 4 + 1) * 17 + j] +
              part[(rr * 4 + 2) * 17 + j] + part[(rr * 4 + 3) * 17 + j] + cls_b[j];
    em[row2 * 17 + j] = (x[row2] != 0) ? v : -1e9f;
  }
}

// ---------------------------------------------------------------------------
// K7: CRF loss per sequence (1 wave / block). res[b] = logZ - score
// ---------------------------------------------------------------------------
__global__ __launch_bounds__(64) void k_crf(
    const float* __restrict__ em, const int* __restrict__ tags,
    const float* __restrict__ mask, const float* __restrict__ trans,
    const float* __restrict__ start_t, const float* __restrict__ end_t,
    float* __restrict__ res) {
  int b = blockIdx.x;
  int lane = threadIdx.x;
  const float* emB = em + (size_t)b * kS * 17;
  const int* tg = tags + b * kS;
  const float* mk = mask + b * kS;

  float tcol[17];
  if (lane < 17) {
#pragma unroll
    for (int i = 0; i < 17; ++i) tcol[i] = trans[i * 17 + lane];
  }
  float sc = 0.f, msum = 0.f;
  for (int t = lane; t < kS; t += 64) msum += mk[t];
  for (int t = 1 + lane; t < kS; t += 64)
    sc += (trans[tg[t - 1] * 17 + tg[t]] + emB[(size_t)t * 17 + tg[t]]) * mk[t];
#pragma unroll
  for (int o = 32; o; o >>= 1) { sc += __shfl_xor(sc, o); msum += __shfl_xor(msum, o); }

  __shared__ float al[17];
  if (lane < 17) al[lane] = start_t[lane] + emB[lane];
  __syncthreads();
  for (int t = 1; t < kS; ++t) {
    float nxt = 0.f;
    if (lane < 17) {
      float v[17]; float mx = -3.4e38f;
#pragma unroll
      for (int i = 0; i < 17; ++i) { v[i] = al[i] + tcol[i]; mx = fmaxf(mx, v[i]); }
      float s = 0.f;
#pragma unroll
      for (int i = 0; i < 17; ++i) s += __expf(v[i] - mx);
      float m = mk[t];
      nxt = (mx + __logf(s) + emB[(size_t)t * 17 + lane]) * m + al[lane] * (1.f - m);
    }
    __syncthreads();
    if (lane < 17) al[lane] = nxt;
    __syncthreads();
  }
  float val = (lane < 17) ? al[lane] + end_t[lane] : -3.4e38f;
  float mx = val;
#pragma unroll
  for (int o = 32; o; o >>= 1) mx = fmaxf(mx, __shfl_xor(mx, o));
  float s = (lane < 17) ? __expf(val - mx) : 0.f;
#pragma unroll
  for (int o = 32; o; o >>= 1) s += __shfl_xor(s, o);
  float logZ = mx + __logf(s);
  if (lane == 0) {
    float score = sc + start_t[tg[0]] + emB[tg[0]];
    int last_real = (int)(msum + 0.5f) - 1;
    if (last_real >= 0) score += end_t[tg[last_real]];
    res[b] = logZ - score;
  }
}

// K8: deterministic mean over 128 sequences -> d_out[0]
__global__ void k_loss(const float* __restrict__ res, float* __restrict__ out) {
  __shared__ float s[128];
  int tid = threadIdx.x;
  s[tid] = res[tid];
  __syncthreads();
  for (int off = 64; off; off >>= 1) {
    if (tid < off) s[tid] += s[tid + off];
    __syncthreads();
  }
  if (tid == 0) out[0] = s[0] / 128.f;
}

}  // namespace

extern "C" void kernel_launch(void* const* d_in, const int* in_sizes, int n_in,
                              void* d_out, int out_size, void* d_ws, size_t ws_size,
                              hipStream_t stream) {
  (void)in_sizes; (void)n_in; (void)out_size; (void)ws_size;
  const int*   x       = (const int*)  d_in[0];
  const int*   tags    = (const int*)  d_in[1];
  const float* mask    = (const float*)d_in[2];
  const float* emb     = (const float*)d_in[3];
  const float* cw3     = (const float*)d_in[4];
  const float* cb3     = (const float*)d_in[5];
  const float* cw5     = (const float*)d_in[6];
  const float* cb5     = (const float*)d_in[7];
  const float* cw7     = (const float*)d_in[8];
  const float* cb7     = (const float*)d_in[9];
  const float* hw_w    = (const float*)d_in[10];
  const float* hw_b    = (const float*)d_in[11];
  const float* hwg_w   = (const float*)d_in[12];
  const float* hwg_b   = (const float*)d_in[13];
  const float* wih0f   = (const float*)d_in[14];
  const float* whh0f   = (const float*)d_in[15];
  const float* b0f     = (const float*)d_in[16];
  const float* wih0b   = (const float*)d_in[17];
  const float* whh0b   = (const float*)d_in[18];
  const float* b0b     = (const float*)d_in[19];
  const float* wih1f   = (const float*)d_in[20];
  const float* whh1f   = (const float*)d_in[21];
  const float* b1f     = (const float*)d_in[22];
  const float* wih1b   = (const float*)d_in[23];
  const float* whh1b   = (const float*)d_in[24];
  const float* b1b     = (const float*)d_in[25];
  const float* cls_w   = (const float*)d_in[26];
  const float* cls_b   = (const float*)d_in[27];
  const float* trans   = (const float*)d_in[28];
  const float* start_t = (const float*)d_in[29];
  const float* end_t   = (const float*)d_in[30];

  // Workspace layout (all activations bf16). Total ~208 MB.
  char* ws = (char*)d_ws;
  const size_t OFF_A  = 393216;                            // tbl is [0, 372KB)
  const size_t SZ_A   = (size_t)kM * 192 * 2;              // conv out bf16 (24 MB)
  const size_t OFF_B  = OFF_A + SZ_A;                      // highway out bf16 (24 MB)
  const size_t OFF_O0 = OFF_B + SZ_A;                      // out0 bf16 (32 MB); em fp32 later
  const size_t OFF_XG = OFF_O0 + (size_t)kM * 256 * 2;     // xg bf16 dual (128 MB)
  float* tbl  = (float*)ws;
  bf16*  bufA = (bf16*)(ws + OFF_A);
  bf16*  bufB = (bf16*)(ws + OFF_B);
  bf16*  out0 = (bf16*)(ws + OFF_O0);
  bf16*  out1 = (bf16*)(ws + OFF_A);                       // bufA/bufB dead by rec1
  bf16*  xg   = (bf16*)(ws + OFF_XG);
  float* em   = (float*)(ws + OFF_O0);                     // out0 dead after proj1
  float* resv = (float*)(ws + OFF_O0 + (size_t)kM * 17 * 4);

  k_table<<<15 * 97, 64, 0, stream>>>(emb, cw3, cw5, cw7, tbl);
  k_conv<<<kB * (kS / 64), 192, 0, stream>>>(x, tbl, cb3, cb5, cb7, bufA);
  k_highway<<<dim3(kM / 64, 3), 256, 0, stream>>>(bufA, hw_w, hw_b, hwg_w, hwg_b, bufB);

  k_proj<<<dim3(kM / 64, 16), 256, 0, stream>>>(bufB, 192, wih0f, b0f, wih0b, b0b, xg);
  k_rec<<<256, 1024, 0, stream>>>(xg, whh0f, whh0b, out0);
  k_proj<<<dim3(kM / 64, 16), 256, 0, stream>>>(out0, 256, wih1f, b1f, wih1b, b1b, xg);
  k_rec<<<256, 1024, 0, stream>>>(xg, whh1f, whh1b, out1);

  k_cls<<<kM / 64, 256, 0, stream>>>(out1, cls_w, cls_b, x, em);
  k_crf<<<kB, 64, 0, stream>>>(em, tags, mask, trans, start_t, end_t, resv);
  k_loss<<<1, 128, 0, stream>>>(resv, (float*)d_out);
}

// Round 4
// 1499.685 us; speedup vs baseline: 1.9607x; 1.5171x over previous
//
#include <hip/hip_runtime.h>
#include <hip/hip_bf16.h>
#include <cstdint>
#include <cstddef>

namespace {

constexpr int kB = 128;
constexpr int kS = 512;
constexpr int kM = kB * kS;   // 65536 rows

typedef __hip_bfloat16 bf16;
typedef __attribute__((ext_vector_type(8))) short short8;
typedef __attribute__((ext_vector_type(4))) float f32x4;

__device__ __forceinline__ float sig_(float x) { return 1.f / (1.f + __expf(-x)); }
__device__ __forceinline__ float tanh_(float x) {
  float e = __expf(2.f * x);
  return 1.f - 2.f / (e + 1.f);
}
__device__ __forceinline__ float b2f(bf16 h) { return __bfloat162float(h); }
__device__ __forceinline__ bf16 f2b(float f) { return __float2bfloat16(f); }

// unpack 8 bf16 (one uint4) -> 8 floats
__device__ __forceinline__ void unpack8(uint4 v, float* o) {
  o[0] = __uint_as_float(v.x << 16); o[1] = __uint_as_float(v.x & 0xffff0000u);
  o[2] = __uint_as_float(v.y << 16); o[3] = __uint_as_float(v.y & 0xffff0000u);
  o[4] = __uint_as_float(v.z << 16); o[5] = __uint_as_float(v.z & 0xffff0000u);
  o[6] = __uint_as_float(v.w << 16); o[7] = __uint_as_float(v.w & 0xffff0000u);
}

__device__ __forceinline__ void gl_lds16(const void* g, void* l) {
  __builtin_amdgcn_global_load_lds((const __attribute__((address_space(1))) void*)g,
                                   (__attribute__((address_space(3))) void*)l, 16, 0, 0);
}

// fp32 -> bf16 weight conversion
__global__ void k_w2b(const float* __restrict__ s, bf16* __restrict__ d, int n) {
  int i = blockIdx.x * 256 + threadIdx.x;
  if (i < n) d[i] = f2b(s[i]);
}

// ---------------------------------------------------------------------------
// K1: per-tap char projection table (fp32, 372KB)
// ---------------------------------------------------------------------------
__global__ void k_table(const float* __restrict__ emb,
                        const float* __restrict__ cw3,
                        const float* __restrict__ cw5,
                        const float* __restrict__ cw7,
                        float* __restrict__ tbl) {
  int e = blockIdx.x;           // 0..15*97-1
  int tap = e / 97, ch = e % 97;
  int f = threadIdx.x;          // 0..63
  const float* w; int kk, dk;
  if (tap < 3)      { w = cw3; kk = 3; dk = tap; }
  else if (tap < 8) { w = cw5; kk = 5; dk = tap - 3; }
  else              { w = cw7; kk = 7; dk = tap - 8; }
  const float* er = emb + ch * 128;
  float s = 0.f;
  for (int c = 0; c < 128; ++c) s = fmaf(er[c], w[(f * 128 + c) * kk + dk], s);
  tbl[(size_t)e * 64 + f] = s;
}

// ---------------------------------------------------------------------------
// K2: conv via table gathers + bias + relu -> bf16 (B*S, 192)
// ---------------------------------------------------------------------------
__global__ void k_conv(const int* __restrict__ x, const float* __restrict__ tbl,
                       const float* __restrict__ cb3, const float* __restrict__ cb5,
                       const float* __restrict__ cb7, bf16* __restrict__ outA) {
  __shared__ int chs[70];
  int b = blockIdx.x >> 3;
  int s0 = (blockIdx.x & 7) << 6;
  int tid = threadIdx.x;
  if (tid < 70) {
    int g = s0 - 3 + tid;
    chs[tid] = (g >= 0 && g < kS) ? x[b * kS + g] : 0;   // char 0 => zero row
  }
  __syncthreads();
  int wv = tid >> 6;
  int f = tid & 63;
  int ntap, tap0, half; const float* cb;
  if (wv == 0)      { ntap = 3; tap0 = 0; half = 1; cb = cb3; }
  else if (wv == 1) { ntap = 5; tap0 = 3; half = 2; cb = cb5; }
  else              { ntap = 7; tap0 = 8; half = 3; cb = cb7; }
  float bias = cb[f];
  for (int p = 0; p < 64; ++p) {
    float acc = bias;
    for (int dk = 0; dk < ntap; ++dk) {
      int c = chs[p + 3 - half + dk];
      acc += tbl[(size_t)((tap0 + dk) * 97 + c) * 64 + f];
    }
    outA[(size_t)(b * kS + s0 + p) * 192 + wv * 64 + f] = f2b(fmaxf(acc, 0.f));
  }
}

// ---------------------------------------------------------------------------
// K3: highway via MFMA, fused dual GEMM (Wa and Wg in one pass).
// BM=128, BN=64, BK=64, 4 waves as 2x2 (wave tile 64x32).
// A bf16 [M,192], Wa/Wg bf16 [192,192]. out bf16.
// ---------------------------------------------------------------------------
__global__ __launch_bounds__(256) void k_hw(
    const bf16* __restrict__ A,
    const bf16* __restrict__ Wa, const float* __restrict__ Ba,
    const bf16* __restrict__ Wg, const float* __restrict__ Bg,
    bf16* __restrict__ outB) {
  __shared__ __align__(16) short As[128 * 64];
  __shared__ __align__(16) short Was[64 * 64];
  __shared__ __align__(16) short Wgs[64 * 64];
  constexpr int K = 192;
  int tid = threadIdx.x;
  int w = tid >> 6, l = tid & 63;
  int m0 = blockIdx.x * 128, n0 = blockIdx.y * 64;
  int wr = w >> 1, wc = w & 1;
  int lr = l >> 3, lc = l & 7;
  f32x4 accA[4][2], accG[4][2];
#pragma unroll
  for (int i = 0; i < 4; ++i)
#pragma unroll
    for (int j = 0; j < 2; ++j) { accA[i][j] = (f32x4)0.f; accG[i][j] = (f32x4)0.f; }

  for (int kc = 0; kc < K; kc += 64) {
    __syncthreads();
#pragma unroll
    for (int i = 0; i < 4; ++i) {
      int r = w * 32 + i * 8;
      gl_lds16(A + (size_t)(m0 + r + lr) * K + kc + lc * 8, &As[r * 64]);
    }
#pragma unroll
    for (int i = 0; i < 2; ++i) {
      int r = w * 16 + i * 8;
      gl_lds16(Wa + (size_t)(n0 + r + lr) * K + kc + lc * 8, &Was[r * 64]);
      gl_lds16(Wg + (size_t)(n0 + r + lr) * K + kc + lc * 8, &Wgs[r * 64]);
    }
    __syncthreads();
#pragma unroll
    for (int kf = 0; kf < 2; ++kf) {
      short8 af[4], ba[2], bg[2];
#pragma unroll
      for (int mt = 0; mt < 4; ++mt)
        af[mt] = *(const short8*)&As[(wr * 64 + mt * 16 + (l & 15)) * 64 + kf * 32 + (l >> 4) * 8];
#pragma unroll
      for (int nt = 0; nt < 2; ++nt) {
        int rn = (wc * 32 + nt * 16 + (l & 15)) * 64 + kf * 32 + (l >> 4) * 8;
        ba[nt] = *(const short8*)&Was[rn];
        bg[nt] = *(const short8*)&Wgs[rn];
      }
#pragma unroll
      for (int mt = 0; mt < 4; ++mt)
#pragma unroll
        for (int nt = 0; nt < 2; ++nt) {
          accA[mt][nt] = __builtin_amdgcn_mfma_f32_16x16x32_bf16(af[mt], ba[nt], accA[mt][nt], 0, 0, 0);
          accG[mt][nt] = __builtin_amdgcn_mfma_f32_16x16x32_bf16(af[mt], bg[nt], accG[mt][nt], 0, 0, 0);
        }
    }
  }
#pragma unroll
  for (int nt = 0; nt < 2; ++nt) {
    int n = n0 + wc * 32 + nt * 16 + (l & 15);
    float bav = Ba[n], bgv = Bg[n];
#pragma unroll
    for (int mt = 0; mt < 4; ++mt) {
      int mb = m0 + wr * 64 + mt * 16 + (l >> 4) * 4;
#pragma unroll
      for (int r = 0; r < 4; ++r) {
        float av = accA[mt][nt][r] + bav;
        float gv = accG[mt][nt][r] + bgv;
        float tt = sig_(gv);
        float orig = b2f(A[(size_t)(mb + r) * K + n]);
        outB[(size_t)(mb + r) * K + n] = f2b(tt * fmaxf(av, 0.f) + (1.f - tt) * orig);
      }
    }
  }
}

// ---------------------------------------------------------------------------
// K4: LSTM input projection via MFMA. BM=128, BN=128, BK=64, 4 waves 2x2.
// A bf16 [M,K], W bf16 [1024,K] (rows 0..511 fwd, 512..1023 bwd).
// xg bf16 [M,1024] = A@W^T + bias.
// ---------------------------------------------------------------------------
__global__ __launch_bounds__(256) void k_pgemm(
    const bf16* __restrict__ A, int K,
    const bf16* __restrict__ W,
    const float* __restrict__ bfw, const float* __restrict__ bbw,
    bf16* __restrict__ xg) {
  __shared__ __align__(16) short As[128 * 64];
  __shared__ __align__(16) short Bs[128 * 64];
  int tid = threadIdx.x;
  int w = tid >> 6, l = tid & 63;
  int m0 = blockIdx.x * 128, n0 = blockIdx.y * 128;
  int wr = w >> 1, wc = w & 1;
  int lr = l >> 3, lc = l & 7;
  f32x4 acc[4][4];
#pragma unroll
  for (int i = 0; i < 4; ++i)
#pragma unroll
    for (int j = 0; j < 4; ++j) acc[i][j] = (f32x4)0.f;

  for (int kc = 0; kc < K; kc += 64) {
    __syncthreads();
#pragma unroll
    for (int i = 0; i < 4; ++i) {
      int r = w * 32 + i * 8;
      gl_lds16(A + (size_t)(m0 + r + lr) * K + kc + lc * 8, &As[r * 64]);
      gl_lds16(W + (size_t)(n0 + r + lr) * K + kc + lc * 8, &Bs[r * 64]);
    }
    __syncthreads();
#pragma unroll
    for (int kf = 0; kf < 2; ++kf) {
      short8 af[4], bfr[4];
#pragma unroll
      for (int mt = 0; mt < 4; ++mt)
        af[mt] = *(const short8*)&As[(wr * 64 + mt * 16 + (l & 15)) * 64 + kf * 32 + (l >> 4) * 8];
#pragma unroll
      for (int nt = 0; nt < 4; ++nt)
        bfr[nt] = *(const short8*)&Bs[(wc * 64 + nt * 16 + (l & 15)) * 64 + kf * 32 + (l >> 4) * 8];
#pragma unroll
      for (int mt = 0; mt < 4; ++mt)
#pragma unroll
        for (int nt = 0; nt < 4; ++nt)
          acc[mt][nt] = __builtin_amdgcn_mfma_f32_16x16x32_bf16(af[mt], bfr[nt], acc[mt][nt], 0, 0, 0);
    }
  }
#pragma unroll
  for (int nt = 0; nt < 4; ++nt) {
    int n = n0 + wc * 64 + nt * 16 + (l & 15);
    float bv = (n < 512) ? bfw[n] : bbw[n - 512];
#pragma unroll
    for (int mt = 0; mt < 4; ++mt) {
      int mb = m0 + wr * 64 + mt * 16 + (l >> 4) * 4;
#pragma unroll
      for (int r = 0; r < 4; ++r)
        xg[(size_t)(mb + r) * 1024 + n] = f2b(acc[mt][nt][r] + bv);
    }
  }
}

// ---------------------------------------------------------------------------
// K5: LSTM recurrence, dual-direction. Grid 256 = (seq 0..127) x (dir 0..1).
// 1024 threads: q = tid&3 (K-quarter, in-lane -> shfl reduce), jj = tid>>2.
// hbuf padded to stride 36 so the 4 q-groups' ds_read_b128 hit distinct banks.
// ---------------------------------------------------------------------------
__global__ __launch_bounds__(1024, 4) void k_rec(
    const bf16* __restrict__ xg,
    const float* __restrict__ whhF, const float* __restrict__ whhB,
    bf16* __restrict__ out) {
  int nb = blockIdx.x;
  int seq = nb & (kB - 1);
  int dir = nb >> 7;
  const float* __restrict__ whh = dir ? whhB : whhF;
  const int col0 = dir * 512;
  const bool rev = (dir == 1);
  int tid = threadIdx.x;
  int q = tid & 3;          // K quarter (in-lane)
  int jj = tid >> 2;        // outputs jj and jj+256

  float w0[32], w1[32];
  {
    const float4* p0 = reinterpret_cast<const float4*>(whh + jj * 128 + q * 32);
    const float4* p1 = reinterpret_cast<const float4*>(whh + (jj + 256) * 128 + q * 32);
#pragma unroll
    for (int v = 0; v < 8; ++v) {
      float4 t0 = p0[v]; w0[4 * v] = t0.x; w0[4 * v + 1] = t0.y; w0[4 * v + 2] = t0.z; w0[4 * v + 3] = t0.w;
      float4 t1 = p1[v]; w1[4 * v] = t1.x; w1[4 * v + 1] = t1.y; w1[4 * v + 2] = t1.z; w1[4 * v + 3] = t1.w;
    }
  }
  __shared__ float hbuf[144];    // 4 slices of 32, stride 36 (16B aligned, bank-spread)
  __shared__ float xbuf[512];
  __shared__ float zs[512];
  if (tid < 144) hbuf[tid] = 0.f;
  float c = 0.f;

  auto base_of = [&](int step) -> size_t {
    int tt = rev ? (kS - 1 - step) : step;
    return (size_t)(seq * kS + tt) * 1024 + col0;
  };
  float xv = 0.f;
  if (tid < 512) xv = b2f(xg[base_of(0) + tid]);
  __syncthreads();

  for (int t = 0; t < kS; ++t) {
    int tt = rev ? (kS - 1 - t) : t;
    float p0 = 0.f, p1 = 0.f;
    const float4* hb = reinterpret_cast<const float4*>(hbuf + q * 36);
#pragma unroll
    for (int v = 0; v < 8; ++v) {
      float4 h4 = hb[v];
      p0 = fmaf(w0[4 * v + 0], h4.x, p0);
      p0 = fmaf(w0[4 * v + 1], h4.y, p0);
      p0 = fmaf(w0[4 * v + 2], h4.z, p0);
      p0 = fmaf(w0[4 * v + 3], h4.w, p0);
      p1 = fmaf(w1[4 * v + 0], h4.x, p1);
      p1 = fmaf(w1[4 * v + 1], h4.y, p1);
      p1 = fmaf(w1[4 * v + 2], h4.z, p1);
      p1 = fmaf(w1[4 * v + 3], h4.w, p1);
    }
    // quad-reduce over K quarters (lanes jj*4+q, q=0..3)
    p0 += __shfl_xor(p0, 1); p0 += __shfl_xor(p0, 2);
    p1 += __shfl_xor(p1, 1); p1 += __shfl_xor(p1, 2);
    if (q == 0) { zs[jj] = p0; zs[jj + 256] = p1; }
    if (tid < 512) xbuf[tid] = xv;
    int tnx = (t + 1 < kS) ? (t + 1) : (kS - 1);
    float xnew = 0.f;
    if (tid < 512) xnew = b2f(xg[base_of(tnx) + tid]);
    __syncthreads();
    if (tid < 128) {
      int u = tid;
      float zi = xbuf[u]       + zs[u];
      float zf = xbuf[u + 128] + zs[u + 128];
      float zg = xbuf[u + 256] + zs[u + 256];
      float zo = xbuf[u + 384] + zs[u + 384];
      float ig = sig_(zi), fg = sig_(zf), gv = tanh_(zg), og = sig_(zo);
      c = fg * c + ig * gv;
      float h = og * tanh_(c);
      hbuf[(u >> 5) * 36 + (u & 31)] = h;
      out[(size_t)(seq * kS + tt) * 256 + dir * 128 + u] = f2b(h);
    }
    xv = xnew;
    __syncthreads();
  }
}

// ---------------------------------------------------------------------------
// K6: classifier + char mask. out1 bf16 -> em fp32 (or NEG)
// ---------------------------------------------------------------------------
__global__ __launch_bounds__(256) void k_cls(
    const bf16* __restrict__ out1, const float* __restrict__ cls_w,
    const float* __restrict__ cls_b, const int* __restrict__ x,
    float* __restrict__ em) {
  __shared__ float W[17 * 256];
  __shared__ float part[64 * 4 * 17];
  int tid = threadIdx.x;
  for (int i = tid; i < 17 * 256; i += 256) W[i] = cls_w[i];
  __syncthreads();
  int r = tid >> 2, q = tid & 3;
  size_t row = (size_t)blockIdx.x * 64 + r;
  float acc[17];
#pragma unroll
  for (int j = 0; j < 17; ++j) acc[j] = 0.f;
  const uint4* a4p = (const uint4*)(out1 + row * 256 + q * 64);
  for (int i = 0; i < 8; ++i) {
    float f8[8]; unpack8(a4p[i], f8);
#pragma unroll
    for (int j = 0; j < 17; ++j) {
      const float* wr = &W[j * 256 + q * 64 + i * 8];
#pragma unroll
      for (int e = 0; e < 8; ++e) acc[j] = fmaf(f8[e], wr[e], acc[j]);
    }
  }
#pragma unroll
  for (int j = 0; j < 17; ++j) part[(r * 4 + q) * 17 + j] = acc[j];
  __syncthreads();
  for (int idx = tid; idx < 64 * 17; idx += 256) {
    int rr = idx / 17, j = idx % 17;
    size_t row2 = (size_t)blockIdx.x * 64 + rr;
    float v = part[(rr * 4 + 0) * 17 + j] + part[(rr * 4 + 1) * 17 + j] +
              part[(rr * 4 + 2) * 17 + j] + part[(rr * 4 + 3) * 17 + j] + cls_b[j];
    em[row2 * 17 + j] = (x[row2] != 0) ? v : -1e9f;
  }
}

// ---------------------------------------------------------------------------
// K7: CRF loss per sequence (1 wave / block). res[b] = logZ - score
// ---------------------------------------------------------------------------
__global__ __launch_bounds__(64) void k_crf(
    const float* __restrict__ em, const int* __restrict__ tags,
    const float* __restrict__ mask, const float* __restrict__ trans,
    const float* __restrict__ start_t, const float* __restrict__ end_t,
    float* __restrict__ res) {
  int b = blockIdx.x;
  int lane = threadIdx.x;
  const float* emB = em + (size_t)b * kS * 17;
  const int* tg = tags + b * kS;
  const float* mk = mask + b * kS;

  float tcol[17];
  if (lane < 17) {
#pragma unroll
    for (int i = 0; i < 17; ++i) tcol[i] = trans[i * 17 + lane];
  }
  float sc = 0.f, msum = 0.f;
  for (int t = lane; t < kS; t += 64) msum += mk[t];
  for (int t = 1 + lane; t < kS; t += 64)
    sc += (trans[tg[t - 1] * 17 + tg[t]] + emB[(size_t)t * 17 + tg[t]]) * mk[t];
#pragma unroll
  for (int o = 32; o; o >>= 1) { sc += __shfl_xor(sc, o); msum += __shfl_xor(msum, o); }

  __shared__ float al[17];
  if (lane < 17) al[lane] = start_t[lane] + emB[lane];
  __syncthreads();
  for (int t = 1; t < kS; ++t) {
    float nxt = 0.f;
    if (lane < 17) {
      float v[17]; float mx = -3.4e38f;
#pragma unroll
      for (int i = 0; i < 17; ++i) { v[i] = al[i] + tcol[i]; mx = fmaxf(mx, v[i]); }
      float s = 0.f;
#pragma unroll
      for (int i = 0; i < 17; ++i) s += __expf(v[i] - mx);
      float m = mk[t];
      nxt = (mx + __logf(s) + emB[(size_t)t * 17 + lane]) * m + al[lane] * (1.f - m);
    }
    __syncthreads();
    if (lane < 17) al[lane] = nxt;
    __syncthreads();
  }
  float val = (lane < 17) ? al[lane] + end_t[lane] : -3.4e38f;
  float mx = val;
#pragma unroll
  for (int o = 32; o; o >>= 1) mx = fmaxf(mx, __shfl_xor(mx, o));
  float s = (lane < 17) ? __expf(val - mx) : 0.f;
#pragma unroll
  for (int o = 32; o; o >>= 1) s += __shfl_xor(s, o);
  float logZ = mx + __logf(s);
  if (lane == 0) {
    float score = sc + start_t[tg[0]] + emB[tg[0]];
    int last_real = (int)(msum + 0.5f) - 1;
    if (last_real >= 0) score += end_t[tg[last_real]];
    res[b] = logZ - score;
  }
}

// K8: deterministic mean over 128 sequences -> d_out[0]
__global__ void k_loss(const float* __restrict__ res, float* __restrict__ out) {
  __shared__ float s[128];
  int tid = threadIdx.x;
  s[tid] = res[tid];
  __syncthreads();
  for (int off = 64; off; off >>= 1) {
    if (tid < off) s[tid] += s[tid + off];
    __syncthreads();
  }
  if (tid == 0) out[0] = s[0] / 128.f;
}

}  // namespace

extern "C" void kernel_launch(void* const* d_in, const int* in_sizes, int n_in,
                              void* d_out, int out_size, void* d_ws, size_t ws_size,
                              hipStream_t stream) {
  (void)in_sizes; (void)n_in; (void)out_size; (void)ws_size;
  const int*   x       = (const int*)  d_in[0];
  const int*   tags    = (const int*)  d_in[1];
  const float* mask    = (const float*)d_in[2];
  const float* emb     = (const float*)d_in[3];
  const float* cw3     = (const float*)d_in[4];
  const float* cb3     = (const float*)d_in[5];
  const float* cw5     = (const float*)d_in[6];
  const float* cb5     = (const float*)d_in[7];
  const float* cw7     = (const float*)d_in[8];
  const float* cb7     = (const float*)d_in[9];
  const float* hw_w    = (const float*)d_in[10];
  const float* hw_b    = (const float*)d_in[11];
  const float* hwg_w   = (const float*)d_in[12];
  const float* hwg_b   = (const float*)d_in[13];
  const float* wih0f   = (const float*)d_in[14];
  const float* whh0f   = (const float*)d_in[15];
  const float* b0f     = (const float*)d_in[16];
  const float* wih0b   = (const float*)d_in[17];
  const float* whh0b   = (const float*)d_in[18];
  const float* b0b     = (const float*)d_in[19];
  const float* wih1f   = (const float*)d_in[20];
  const float* whh1f   = (const float*)d_in[21];
  const float* b1f     = (const float*)d_in[22];
  const float* wih1b   = (const float*)d_in[23];
  const float* whh1b   = (const float*)d_in[24];
  const float* b1b     = (const float*)d_in[25];
  const float* cls_w   = (const float*)d_in[26];
  const float* cls_b   = (const float*)d_in[27];
  const float* trans   = (const float*)d_in[28];
  const float* start_t = (const float*)d_in[29];
  const float* end_t   = (const float*)d_in[30];

  // Workspace layout. tbl fp32 | bf16 weights | bf16 activations. ~210 MB.
  char* ws = (char*)d_ws;
  const size_t OFF_W0 = 393216;                            // tbl is [0, 372KB)
  const size_t OFF_W1 = OFF_W0 + (size_t)1024 * 192 * 2;   // 384KB
  const size_t OFF_WA = OFF_W1 + (size_t)1024 * 256 * 2;   // 512KB
  const size_t OFF_WG = OFF_WA + (size_t)192 * 192 * 2;
  const size_t OFF_A  = OFF_WG + (size_t)192 * 192 * 2;
  const size_t SZ_A   = (size_t)kM * 192 * 2;              // 24 MB
  const size_t OFF_B  = OFF_A + SZ_A;
  const size_t OFF_O0 = OFF_B + SZ_A;                      // out0 bf16 (32MB); em fp32 later
  const size_t OFF_XG = OFF_O0 + (size_t)kM * 256 * 2;     // xg bf16 dual (128MB)
  float* tbl  = (float*)ws;
  bf16*  W0b  = (bf16*)(ws + OFF_W0);
  bf16*  W1b  = (bf16*)(ws + OFF_W1);
  bf16*  WAb  = (bf16*)(ws + OFF_WA);
  bf16*  WGb  = (bf16*)(ws + OFF_WG);
  bf16*  bufA = (bf16*)(ws + OFF_A);
  bf16*  bufB = (bf16*)(ws + OFF_B);
  bf16*  out0 = (bf16*)(ws + OFF_O0);
  bf16*  out1 = (bf16*)(ws + OFF_A);                       // bufA/bufB dead by rec1
  bf16*  xg   = (bf16*)(ws + OFF_XG);
  float* em   = (float*)(ws + OFF_O0);                     // out0 dead after proj1
  float* resv = (float*)(ws + OFF_O0 + (size_t)kM * 17 * 4);

  // weight conversion prepass
  k_w2b<<<384, 256, 0, stream>>>(wih0f, W0b, 512 * 192);
  k_w2b<<<384, 256, 0, stream>>>(wih0b, W0b + 512 * 192, 512 * 192);
  k_w2b<<<512, 256, 0, stream>>>(wih1f, W1b, 512 * 256);
  k_w2b<<<512, 256, 0, stream>>>(wih1b, W1b + 512 * 256, 512 * 256);
  k_w2b<<<144, 256, 0, stream>>>(hw_w, WAb, 192 * 192);
  k_w2b<<<144, 256, 0, stream>>>(hwg_w, WGb, 192 * 192);

  k_table<<<15 * 97, 64, 0, stream>>>(emb, cw3, cw5, cw7, tbl);
  k_conv<<<kB * (kS / 64), 192, 0, stream>>>(x, tbl, cb3, cb5, cb7, bufA);
  k_hw<<<dim3(kM / 128, 3), 256, 0, stream>>>(bufA, WAb, hw_b, WGb, hwg_b, bufB);

  k_pgemm<<<dim3(kM / 128, 8), 256, 0, stream>>>(bufB, 192, W0b, b0f, b0b, xg);
  k_rec<<<256, 1024, 0, stream>>>(xg, whh0f, whh0b, out0);
  k_pgemm<<<dim3(kM / 128, 8), 256, 0, stream>>>(out0, 256, W1b, b1f, b1b, xg);
  k_rec<<<256, 1024, 0, stream>>>(xg, whh1f, whh1b, out1);

  k_cls<<<kM / 64, 256, 0, stream>>>(out1, cls_w, cls_b, x, em);
  k_crf<<<kB, 64, 0, stream>>>(em, tags, mask, trans, start_t, end_t, resv);
  k_loss<<<1, 128, 0, stream>>>(resv, (float*)d_out);
}